// Round 15
// baseline (274.494 us; speedup 1.0000x reference)
//
#include <hip/hip_runtime.h>
#include <stdint.h>

// ---------- bf16 helpers (storage = unsigned short) ----------
__device__ __forceinline__ float b2f(unsigned short u) {
    union { uint32_t i; float f; } v; v.i = ((uint32_t)u) << 16; return v.f;
}
__device__ __forceinline__ unsigned short f2b(float f) {
    union { float f; uint32_t i; } v; v.f = f;
    uint32_t r = v.i + 0x7fffu + ((v.i >> 16) & 1u);   // RNE
    return (unsigned short)(r >> 16);
}

typedef __bf16 bf16x8 __attribute__((ext_vector_type(8)));
typedef float  f32x16 __attribute__((ext_vector_type(16)));

// ---------------------------------------------------------------------------
// build_W_fused + prep_all: ONE launch for all pre-GEMM work (R11-verified).
// ---------------------------------------------------------------------------
template<int N1, int N2, int N3, int M1, int M2, int M3>
__device__ __forceinline__ void build_W_fused(int blk,
                                              const float* __restrict__ c0,
                                              const float* __restrict__ c1,
                                              const float* __restrict__ c2,
                                              unsigned short* __restrict__ W,
                                              float* __restrict__ S) {
    constexpr int K = N1 * N2 * N3;
    const int n2 = blk / M2;
    const int m2 = blk % M2;

    for (int e = threadIdx.x; e < 16 * N3 * M3; e += 256) {
        const int m3 = e % M3;
        const int n3 = (e / M3) % N3;
        const int r1 = e / (M3 * N3);
        const float* c1p = c1 + ((r1 * N2 + n2) * M2 + m2) * 16;
        float s = 0.f;
#pragma unroll
        for (int r2 = 0; r2 < 16; ++r2)
            s += c1p[r2] * c2[(r2 * N3 + n3) * M3 + m3];
        S[e] = s;
    }
    __syncthreads();

    for (int e = threadIdx.x; e < N1 * M1 * M3; e += 256) {
        const int m3 = e % M3;
        const int m1 = (e / M3) % M1;
        const int n1 = e / (M3 * M1);
        const float* c0p = c0 + (n1 * M1 + m1) * 16;
        float acc[N3] = {};
#pragma unroll
        for (int r1 = 0; r1 < 16; ++r1) {
            const float c0v = c0p[r1];
#pragma unroll
            for (int n3 = 0; n3 < N3; ++n3)
                acc[n3] += c0v * S[(r1 * N3 + n3) * M3 + m3];
        }
        unsigned short ob[N3];
#pragma unroll
        for (int n3 = 0; n3 < N3; ++n3) ob[n3] = f2b(acc[n3]);
        unsigned short* dst = W + (size_t)((m1 * M2 + m2) * M3 + m3) * K
                                + (n1 * N2 + n2) * N3;
#pragma unroll
        for (int c = 0; c < N3 / 8; ++c)
            ((int4*)dst)[c] = ((const int4*)ob)[c];
    }
}

__global__ __launch_bounds__(256)
void prep_all(const float* __restrict__ c10, const float* __restrict__ c11,
              const float* __restrict__ c12,
              const float* __restrict__ c20, const float* __restrict__ c21,
              const float* __restrict__ c22,
              const float* __restrict__ x, unsigned short* __restrict__ xb,
              unsigned short* __restrict__ W1, unsigned short* __restrict__ W2) {
    __shared__ float S[16 * 128];
    const int b = blockIdx.x;
    if (b < 256) {
        build_W_fused<8, 16, 8, 16, 16, 16>(b, c10, c11, c12, W1, S);
    } else if (b < 512) {
        build_W_fused<16, 16, 16, 8, 16, 8>(b - 256, c20, c21, c22, W2, S);
    } else {
        const int t = (b - 512) * 256 + threadIdx.x;
        const float4* p = (const float4*)(x + (size_t)t * 8);
        float4 f0 = p[0], f1 = p[1];
        int4 o;
        o.x = (uint32_t)f2b(f0.x) | ((uint32_t)f2b(f0.y) << 16);
        o.y = (uint32_t)f2b(f0.z) | ((uint32_t)f2b(f0.w) << 16);
        o.z = (uint32_t)f2b(f1.x) | ((uint32_t)f2b(f1.y) << 16);
        o.w = (uint32_t)f2b(f1.z) | ((uint32_t)f2b(f1.w) << 16);
        ((int4*)xb)[t] = o;
    }
}

// ---------------------------------------------------------------------------
// bias_fill: out[r][c] = bias[c]  (f32).  Runs AFTER GEMM1 (xb scratch dead).
// ---------------------------------------------------------------------------
__global__ __launch_bounds__(256)
void bias_fill(const float* __restrict__ b, float4* __restrict__ out) {
    int t = blockIdx.x * 256 + threadIdx.x;
    out[t] = ((const float4*)b)[t & 255];
}

// ---------------------------------------------------------------------------
// Fallback-path kernels (small workspace): verified R5-R7 chain.
// ---------------------------------------------------------------------------
template<int N3, int M3>
__device__ __forceinline__ void build_T_body(int e,
                                             const float* __restrict__ c1,
                                             const float* __restrict__ c2,
                                             float* __restrict__ T) {
    int m3 = e % M3;
    int t  = e / M3;
    int n3 = t % N3;
    int rm = t / N3;
    float s = 0.f;
#pragma unroll
    for (int r2 = 0; r2 < 16; ++r2)
        s += c1[rm * 16 + r2] * c2[(r2 * N3 + n3) * M3 + m3];
    T[e] = s;
}

__global__ __launch_bounds__(256)
void prep_stage1(const float* __restrict__ c11, const float* __restrict__ c12,
                 float* __restrict__ T1,
                 const float* __restrict__ c21, const float* __restrict__ c22,
                 float* __restrict__ T2,
                 const float* __restrict__ x, unsigned short* __restrict__ xb) {
    const int b = blockIdx.x;
    if (b < 2048) {
        build_T_body<8, 16>(b * 256 + threadIdx.x, c11, c12, T1);
    } else if (b < 4096) {
        build_T_body<16, 8>((b - 2048) * 256 + threadIdx.x, c21, c22, T2);
    } else {
        const int t = (b - 4096) * 256 + threadIdx.x;
        const float4* p = (const float4*)(x + (size_t)t * 8);
        float4 f0 = p[0], f1 = p[1];
        int4 o;
        o.x = (uint32_t)f2b(f0.x) | ((uint32_t)f2b(f0.y) << 16);
        o.y = (uint32_t)f2b(f0.z) | ((uint32_t)f2b(f0.w) << 16);
        o.z = (uint32_t)f2b(f1.x) | ((uint32_t)f2b(f1.y) << 16);
        o.w = (uint32_t)f2b(f1.z) | ((uint32_t)f2b(f1.w) << 16);
        ((int4*)xb)[t] = o;
    }
}

template<int N1, int N2, int N3, int M1, int M2, int M3>
__device__ __forceinline__ void build_W_body(int t,
                                             const float* __restrict__ c0,
                                             const float* __restrict__ T,
                                             unsigned short* __restrict__ W) {
    constexpr int K = N1 * N2 * N3;
    int m3 = t % M3;
    int m2 = (t / M3) % M2;
    int n2 = (t / (M3 * M2)) % N2;
    int m1 = (t / (M3 * M2 * N2)) % M1;
    int n1 =  t / (M3 * M2 * N2 * M1);

    float c0r[16];
    const float4* c0p = (const float4*)(c0 + (n1 * M1 + m1) * 16);
#pragma unroll
    for (int i = 0; i < 4; ++i) ((float4*)c0r)[i] = c0p[i];

    float acc[N3] = {};
#pragma unroll
    for (int r1 = 0; r1 < 16; ++r1) {
        const float* Tp = T + (size_t)(((r1 * 16 + n2) * 16 + m2) * N3) * M3 + m3;
#pragma unroll
        for (int n3 = 0; n3 < N3; ++n3)
            acc[n3] += c0r[r1] * Tp[n3 * M3];
    }

    unsigned short ob[N3];
#pragma unroll
    for (int n3 = 0; n3 < N3; ++n3) ob[n3] = f2b(acc[n3]);

    unsigned short* dst = W + (size_t)((m1 * M2 + m2) * M3 + m3) * K
                            + (n1 * N2 + n2) * N3;
#pragma unroll
    for (int c = 0; c < N3 / 8; ++c)
        ((int4*)dst)[c] = ((const int4*)ob)[c];
}

template<int N1, int N2, int N3, int M1, int M2, int M3>
__global__ __launch_bounds__(256)
void build_W(const float* __restrict__ c0, const float* __restrict__ T,
             unsigned short* __restrict__ W) {
    build_W_body<N1, N2, N3, M1, M2, M3>(blockIdx.x * 256 + threadIdx.x, c0, T, W);
}

// ---------------------------------------------------------------------------
// gemm_big: 256x256 tile, 8 waves, 128x64 WAVE TILE (R13-verified, 50.6us).
// 2-phase dbuf loop: STAGE(buf^1, t+1) -> COMPUTE(buf) -> __syncthreads.
// DO NOT hold full-tile frags in regs (R14: 24 frags + 128 acc spills --
// WRITE_SIZE 92.8MB, 119us).  This 2-phase form IS the measured ceiling
// for this family (687 TF == m230's 682).
// Staging pre-swizzled gload_lds, key(r)=(r&7)^((r>>3)&7), 0 conflicts.
// C/D map (m74/m101): col=lane&31, row=(reg&3)+8*(reg>>2)+4*(lane>>5).
// ---------------------------------------------------------------------------
template<int BM, int BN, int KTOT, int GX, bool DO_GELU>
__global__ __launch_bounds__(512, 2)
void gemm_big(const unsigned short* __restrict__ A,
              const unsigned short* __restrict__ Bt,
              const float* __restrict__ bias,
              unsigned short* __restrict__ C,
              int Ncols)
{
    constexpr int BK   = 64;
    constexpr int NT   = KTOT / BK;
    constexpr int ASZ  = BM * BK;          // 16384 elems (32KB)
    constexpr int BUFE = (BM + BN) * BK;   // 32768 elems (64KB)
    constexpr int ACH  = BM / 64;          // 4
    constexpr int BCH  = BN / 64;          // 4
    constexpr int FI   = 4, FJ = 2;        // 128x64 wave tile

    extern __shared__ unsigned short sh[];   // [2][BUFE]

    const int tid   = threadIdx.x;
    const int lane  = tid & 63;
    const int wave  = tid >> 6;            // 0..7
    const int m32   = lane & 31;
    const int khalf = lane >> 5;
    const int waveM = (wave >> 2) * 128;   // 2 M-waves
    const int waveN = (wave & 3) * 64;     // 4 N-waves
    const int srow  = tid >> 3;            // 0..63
    const int sslot = tid & 7;

    // XCD-chunked bijective block swizzle (total = 256, %8==0)
    int lin = (int)blockIdx.y * GX + (int)blockIdx.x;
    const int total = GX * (int)gridDim.y;
    lin = (lin & 7) * (total >> 3) + (lin >> 3);
    const int colBase = (lin % GX) * BN;
    const int rowBase = (lin / GX) * BM;

#define BG_STAGE(B_, K0_)                                                     \
    {                                                                         \
        _Pragma("unroll")                                                     \
        for (int c = 0; c < ACH; ++c) {                                       \
            const int r  = c * 64 + srow;                                     \
            const int jg = sslot ^ (r & 7) ^ ((r >> 3) & 7);                  \
            const unsigned short* src = A +                                   \
                (size_t)(rowBase + r) * KTOT + (K0_) + jg * 8;                \
            unsigned short* dst = sh + (B_) * BUFE + c * 4096 + wave * 512;   \
            __builtin_amdgcn_global_load_lds(                                 \
                (const __attribute__((address_space(1))) void*)src,           \
                (__attribute__((address_space(3))) void*)dst, 16, 0, 0);      \
        }                                                                     \
        _Pragma("unroll")                                                     \
        for (int c = 0; c < BCH; ++c) {                                       \
            const int r  = c * 64 + srow;                                     \
            const int jg = sslot ^ (r & 7) ^ ((r >> 3) & 7);                  \
            const unsigned short* src = Bt +                                  \
                (size_t)(colBase + r) * KTOT + (K0_) + jg * 8;                \
            unsigned short* dst = sh + (B_) * BUFE + ASZ + c * 4096           \
                                  + wave * 512;                               \
            __builtin_amdgcn_global_load_lds(                                 \
                (const __attribute__((address_space(1))) void*)src,           \
                (__attribute__((address_space(3))) void*)dst, 16, 0, 0);      \
        }                                                                     \
    }

    f32x16 acc[FI][FJ] = {};

    BG_STAGE(0, 0)
    __syncthreads();

    int buf = 0;
    for (int t = 0; t < NT; ++t) {
        if (t + 1 < NT) BG_STAGE(buf ^ 1, (t + 1) * BK)

        const unsigned short* Ab = sh + buf * BUFE;
        const unsigned short* Bb = Ab + ASZ;
#pragma unroll
        for (int ks = 0; ks < 4; ++ks) {
            bf16x8 a_f[FI], b_f[FJ];
            const int g = ks * 2 + khalf;
#pragma unroll
            for (int i = 0; i < FI; ++i) {
                const int r = waveM + i * 32 + m32;
                const int key = (r & 7) ^ ((r >> 3) & 7);
                a_f[i] = *(const bf16x8*)&Ab[r * BK + ((g ^ key) << 3)];
            }
#pragma unroll
            for (int j = 0; j < FJ; ++j) {
                const int r = waveN + j * 32 + m32;
                const int key = (r & 7) ^ ((r >> 3) & 7);
                b_f[j] = *(const bf16x8*)&Bb[r * BK + ((g ^ key) << 3)];
            }
#pragma unroll
            for (int i = 0; i < FI; ++i)
#pragma unroll
                for (int j = 0; j < FJ; ++j)
                    acc[i][j] = __builtin_amdgcn_mfma_f32_32x32x16_bf16(
                        a_f[i], b_f[j], acc[i][j], 0, 0, 0);
        }
        __syncthreads();
        buf ^= 1;
    }
#undef BG_STAGE

    // epilogue: col=lane&31, row=(reg&3)+8*(reg>>2)+4*(lane>>5)
#pragma unroll
    for (int i = 0; i < FI; ++i) {
#pragma unroll
        for (int j = 0; j < FJ; ++j) {
            const int col = colBase + waveN + j * 32 + m32;
            const float bv = bias[col];
#pragma unroll
            for (int reg = 0; reg < 16; ++reg) {
                const int row = rowBase + waveM + i * 32 +
                                (reg & 3) + 8 * (reg >> 2) + 4 * khalf;
                float z = acc[i][j][reg] + bv;
                if (DO_GELU)
                    z = 0.5f * z * (1.f + erff(z * 0.70710678118654752f));
                C[(size_t)row * Ncols + col] = f2b(z);
            }
        }
    }
}

// ---------------------------------------------------------------------------
// gemm_sb2: GEMM2 with the R13-proven 128x64 WAVE TILE on 256x128 geometry.
//
// gemm_sb's exact single-buffer 2-barrier loop (R10-R13-verified), but
// 256 threads as 2M x 2N waves of 128x64 (FI=4, FJ=2) -- the read-ratio
// that bought GEMM1 +14% in R13.  N=1024 allows only 8 col-tiles at
// BN=128, so K-SPLIT=2 (grid 8x16x2 = 256 blocks, %8==0) with f32
// unsafeAtomicAdd into bias-prefilled d_out (R2/R9-verified machinery).
// LDS 48KB used+requested -> floor(160/48)=3 blocks/CU (gload_lds-safe);
// 256 blocks co-resident in one round.
// ---------------------------------------------------------------------------
template<int BM, int BN, int KCH, int KSTR, int GX, int GY>
__global__ __launch_bounds__(256, 3)
void gemm_sb2(const unsigned short* __restrict__ A,
              const unsigned short* __restrict__ Bt,
              float* __restrict__ Cv,
              int Ncols)
{
    constexpr int BK  = 64;
    constexpr int NT  = KCH / BK;
    constexpr int ASZ = BM * BK;           // 16384 elems
    constexpr int ACH = BM / 32;           // 8 staging issues (4KB each)
    constexpr int BCH = BN / 32;           // 4
    constexpr int FI  = 4, FJ = 2;         // 128x64 wave tile

    extern __shared__ unsigned short sh[];   // 48KB

    const int tid   = threadIdx.x;
    const int lane  = tid & 63;
    const int wave  = tid >> 6;            // 0..3
    const int m32   = lane & 31;
    const int khalf = lane >> 5;
    const int waveM = (wave >> 1) * 128;   // 2 M-waves
    const int waveN = (wave & 1) * 64;     // 2 N-waves
    const int srow  = tid >> 3;            // 0..31
    const int sslot = tid & 7;

    // XCD-chunked bijective block swizzle over (x,y,z); total = 256
    int lin = ((int)blockIdx.z * GY + (int)blockIdx.y) * GX + (int)blockIdx.x;
    const int total = GX * GY * (int)gridDim.z;
    lin = (lin & 7) * (total >> 3) + (lin >> 3);
    const int colBase = (lin % GX) * BN;
    const int rowBase = ((lin / GX) % GY) * BM;
    const int kOff    = (lin / (GX * GY)) * KCH;

#define S2_STAGE(K0_)                                                         \
    {                                                                         \
        _Pragma("unroll")                                                     \
        for (int c = 0; c < ACH; ++c) {                                       \
            const int r  = c * 32 + srow;                                     \
            const int jg = sslot ^ (r & 7) ^ ((r >> 3) & 7);                  \
            const unsigned short* src = A +                                   \
                (size_t)(rowBase + r) * KSTR + (K0_) + jg * 8;                \
            unsigned short* dst = sh + c * 2048 + wave * 512;                 \
            __builtin_amdgcn_global_load_lds(                                 \
                (const __attribute__((address_space(1))) void*)src,           \
                (__attribute__((address_space(3))) void*)dst, 16, 0, 0);      \
        }                                                                     \
        _Pragma("unroll")                                                     \
        for (int c = 0; c < BCH; ++c) {                                       \
            const int r  = c * 32 + srow;                                     \
            const int jg = sslot ^ (r & 7) ^ ((r >> 3) & 7);                  \
            const unsigned short* src = Bt +                                  \
                (size_t)(colBase + r) * KSTR + (K0_) + jg * 8;                \
            unsigned short* dst = sh + ASZ + c * 2048 + wave * 512;           \
            __builtin_amdgcn_global_load_lds(                                 \
                (const __attribute__((address_space(1))) void*)src,           \
                (__attribute__((address_space(3))) void*)dst, 16, 0, 0);      \
        }                                                                     \
    }

    f32x16 acc[FI][FJ] = {};

    for (int t = 0; t < NT; ++t) {
        S2_STAGE(kOff + t * BK)
        __syncthreads();                   // vm drain: tile t landed

        const unsigned short* Ab = sh;
        const unsigned short* Bb = sh + ASZ;
#pragma unroll
        for (int ks = 0; ks < 4; ++ks) {
            bf16x8 a_f[FI], b_f[FJ];
            const int g = ks * 2 + khalf;
#pragma unroll
            for (int i = 0; i < FI; ++i) {
                const int r = waveM + i * 32 + m32;
                const int key = (r & 7) ^ ((r >> 3) & 7);
                a_f[i] = *(const bf16x8*)&Ab[r * BK + ((g ^ key) << 3)];
            }
#pragma unroll
            for (int j = 0; j < FJ; ++j) {
                const int r = waveN + j * 32 + m32;
                const int key = (r & 7) ^ ((r >> 3) & 7);
                b_f[j] = *(const bf16x8*)&Bb[r * BK + ((g ^ key) << 3)];
            }
#pragma unroll
            for (int i = 0; i < FI; ++i)
#pragma unroll
                for (int j = 0; j < FJ; ++j)
                    acc[i][j] = __builtin_amdgcn_mfma_f32_32x32x16_bf16(
                        a_f[i], b_f[j], acc[i][j], 0, 0, 0);
        }
        if (t + 1 < NT) __syncthreads();   // reads done before next stage
    }
#undef S2_STAGE

    // epilogue: atomic += into bias-prefilled f32 output
#pragma unroll
    for (int i = 0; i < FI; ++i) {
#pragma unroll
        for (int j = 0; j < FJ; ++j) {
            const int col = colBase + waveN + j * 32 + m32;
#pragma unroll
            for (int reg = 0; reg < 16; ++reg) {
                const int row = rowBase + waveM + i * 32 +
                                (reg & 3) + 8 * (reg >> 2) + 4 * khalf;
                unsafeAtomicAdd(Cv + (size_t)row * Ncols + col,
                                acc[i][j][reg]);
            }
        }
    }
}

// ---------------------------------------------------------------------------
// gemm_pc: R0's producer-consumer GEMM (fallback path only).
// ---------------------------------------------------------------------------
#define PC_COMPUTE(BUF)                                                       \
    {                                                                         \
        _Pragma("unroll")                                                     \
        for (int ks = 0; ks < 4; ++ks) {                                      \
            bf16x8 a_f[FI], b_f[FJ];                                          \
            _Pragma("unroll")                                                 \
            for (int i = 0; i < FI; ++i) {                                    \
                const int key = (m32 & 7) ^                                   \
                    (((waveM >> 3) + 4 * i + (m32 >> 3)) & 7);                \
                const int slot = ((ks * 2 + khalf) ^ key) * 8;                \
                a_f[i] = *(const bf16x8*)&As[(BUF) * ASZ +                    \
                          (waveM + i * 32 + m32) * BK + slot];                \
            }                                                                 \
            _Pragma("unroll")                                                 \
            for (int j = 0; j < FJ; ++j) {                                    \
                const int key = (m32 & 7) ^                                   \
                    (((waveN >> 3) + 4 * j + (m32 >> 3)) & 7);                \
                const int slot = ((ks * 2 + khalf) ^ key) * 8;                \
                b_f[j] = *(const bf16x8*)&Bs[(BUF) * BSZ +                    \
                          (waveN + j * 32 + m32) * BK + slot];                \
            }                                                                 \
            _Pragma("unroll")                                                 \
            for (int i = 0; i < FI; ++i)                                      \
                _Pragma("unroll")                                             \
                for (int j = 0; j < FJ; ++j)                                  \
                    acc[i][j] = __builtin_amdgcn_mfma_f32_32x32x16_bf16(      \
                        a_f[i], b_f[j], acc[i][j], 0, 0, 0);                  \
        }                                                                     \
    }

template<int BM, int BN, int KTOT, bool DO_GELU, bool A_F32, bool C_F32>
__global__ __launch_bounds__(512, 4)
void gemm_pc(const void* __restrict__ Av,
             const unsigned short* __restrict__ Bt,
             const float* __restrict__ bias,
             void* __restrict__ Cv,
             int Ncols) {
    constexpr int BK  = 64;
    constexpr int CA  = BM / 8;
    constexpr int CB  = BN / 8;
    constexpr int PA  = CA / 4;
    constexpr int PB  = CB / 4;
    constexpr int FI  = BM / 64;
    constexpr int FJ  = BN / 64;
    constexpr int ASZ = BM * BK;
    constexpr int BSZ = BN * BK;
    __shared__ unsigned short As[2 * ASZ];
    __shared__ unsigned short Bs[2 * BSZ];

    const int tid  = threadIdx.x;
    const int lane = tid & 63;
    const int wave = tid >> 6;
    const int rowBase = blockIdx.y * BM;
    const int colBase = blockIdx.x * BN;

    const int lr    = lane >> 3;
    const int jj    = lane & 7;
    const int m32   = lane & 31;
    const int khalf = lane >> 5;

    if (wave >= 4) {
        const int pw = wave - 4;
#pragma unroll
        for (int it = 0; it < PA; ++it) {
            const int c  = pw * PA + it;
            const int jg = jj ^ lr ^ (c & 7);
            const size_t aoff = (size_t)(rowBase + c * 8 + lr) * KTOT + jg * 8;
            int4 v;
            if (A_F32) {
                const float* ga = (const float*)Av + aoff;
                float4 f0 = *(const float4*)ga;
                float4 f1 = *(const float4*)(ga + 4);
                v.x = (uint32_t)f2b(f0.x) | ((uint32_t)f2b(f0.y) << 16);
                v.y = (uint32_t)f2b(f0.z) | ((uint32_t)f2b(f0.w) << 16);
                v.z = (uint32_t)f2b(f1.x) | ((uint32_t)f2b(f1.y) << 16);
                v.w = (uint32_t)f2b(f1.z) | ((uint32_t)f2b(f1.w) << 16);
            } else {
                v = *(const int4*)((const unsigned short*)Av + aoff);
            }
            *(int4*)&As[c * 512 + lane * 8] = v;
        }
#pragma unroll
        for (int it = 0; it < PB; ++it) {
            const int c  = pw * PB + it;
            const int jg = jj ^ lr ^ (c & 7);
            *(int4*)&Bs[c * 512 + lane * 8] =
                *(const int4*)(Bt + (size_t)(colBase + c * 8 + lr) * KTOT + jg * 8);
        }
        __syncthreads();

        int buf = 1;
        for (int k0 = BK; k0 < KTOT; k0 += BK) {
            int4 aR[PA], bR[PB];
#pragma unroll
            for (int it = 0; it < PA; ++it) {
                const int c  = pw * PA + it;
                const int jg = jj ^ lr ^ (c & 7);
                const size_t aoff = (size_t)(rowBase + c * 8 + lr) * KTOT + k0 + jg * 8;
                if (A_F32) {
                    const float* ga = (const float*)Av + aoff;
                    float4 f0 = *(const float4*)ga;
                    float4 f1 = *(const float4*)(ga + 4);
                    int4 v;
                    v.x = (uint32_t)f2b(f0.x) | ((uint32_t)f2b(f0.y) << 16);
                    v.y = (uint32_t)f2b(f0.z) | ((uint32_t)f2b(f0.w) << 16);
                    v.z = (uint32_t)f2b(f1.x) | ((uint32_t)f2b(f1.y) << 16);
                    v.w = (uint32_t)f2b(f1.z) | ((uint32_t)f2b(f1.w) << 16);
                    aR[it] = v;
                } else {
                    aR[it] = *(const int4*)((const unsigned short*)Av + aoff);
                }
            }
#pragma unroll
            for (int it = 0; it < PB; ++it) {
                const int c  = pw * PB + it;
                const int jg = jj ^ lr ^ (c & 7);
                bR[it] = *(const int4*)(Bt + (size_t)(colBase + c * 8 + lr) * KTOT + k0 + jg * 8);
            }
#pragma unroll
            for (int it = 0; it < PA; ++it) {
                const int c = pw * PA + it;
                *(int4*)&As[buf * ASZ + c * 512 + lane * 8] = aR[it];
            }
#pragma unroll
            for (int it = 0; it < PB; ++it) {
                const int c = pw * PB + it;
                *(int4*)&Bs[buf * BSZ + c * 512 + lane * 8] = bR[it];
            }
            __syncthreads();
            buf ^= 1;
        }
    } else {
        const int waveM = (wave >> 1) * (BM / 2);
        const int waveN = (wave & 1) * (BN / 2);
        f32x16 acc[FI][FJ] = {};

        __syncthreads();

        int cur = 0;
        for (int k0 = BK; k0 < KTOT; k0 += BK) {
            PC_COMPUTE(cur)
            __syncthreads();
            cur ^= 1;
        }
        PC_COMPUTE(cur)

#pragma unroll
        for (int i = 0; i < FI; ++i) {
#pragma unroll
            for (int j = 0; j < FJ; ++j) {
                const int col = colBase + waveN + j * 32 + m32;
                const float bv = bias[col];
#pragma unroll
                for (int reg = 0; reg < 16; ++reg) {
                    const int row = rowBase + waveM + i * 32 +
                                    (reg & 3) + 8 * (reg >> 2) + 4 * khalf;
                    float z = acc[i][j][reg] + bv;
                    if (DO_GELU)
                        z = 0.5f * z * (1.f + erff(z * 0.70710678118654752f));
                    const size_t off = (size_t)row * Ncols + col;
                    if (C_F32) ((float*)Cv)[off] = z;
                    else       ((unsigned short*)Cv)[off] = f2b(z);
                }
            }
        }
    }
}

// ---------------------------------------------------------------------------
extern "C" void kernel_launch(void* const* d_in, const int* in_sizes, int n_in,
                              void* d_out, int out_size, void* d_ws, size_t ws_size,
                              hipStream_t stream) {
    const float* x      = (const float*)d_in[0];   // [4096,1024] fp32
    const float* fc1_c0 = (const float*)d_in[1];
    const float* fc1_c1 = (const float*)d_in[2];
    const float* fc1_c2 = (const float*)d_in[3];
    const float* fc1_b  = (const float*)d_in[4];
    const float* fc2_c0 = (const float*)d_in[5];
    const float* fc2_c1 = (const float*)d_in[6];
    const float* fc2_c2 = (const float*)d_in[7];
    const float* fc2_b  = (const float*)d_in[8];

    char* ws = (char*)d_ws;
    const bool big = ws_size >= (48ull << 20);

    constexpr int DLDSB = 2 * (256 + 256) * 64 * 2;  // 128 KB dbuf (gemm_big)
    constexpr int DLDS2 = (256 + 128) * 64 * 2;      // 48 KB (gemm_sb2, 3/CU)

    static bool attr_done = false;
    if (!attr_done) {
        attr_done = true;
        (void)hipFuncSetAttribute(
            reinterpret_cast<const void*>(&gemm_big<256, 256, 1024, 16, true>),
            hipFuncAttributeMaxDynamicSharedMemorySize, DLDSB);
    }

    if (big) {
        // d_out scratch: xb bf16 [0,8M) -- dead after GEMM1; bias_fill then
        // overwrites d_out; GEMM2 atomically accumulates into it.
        // ws: W1 [0,8M), W2 [8,16M), h bf16 [16,48M)
        unsigned short* xb = (unsigned short*)d_out;
        unsigned short* W1 = (unsigned short*)ws;
        unsigned short* W2 = (unsigned short*)(ws + (8u << 20));
        unsigned short* h  = (unsigned short*)(ws + (16u << 20));

        // K0: all pre-GEMM work in one launch (R11-verified)
        prep_all<<<2560, 256, 0, stream>>>(fc1_c0, fc1_c1, fc1_c2,
                                           fc2_c0, fc2_c1, fc2_c2,
                                           x, xb, W1, W2);
        // K1: GEMM1 -- R13-verified gemm_big (50.6us)
        gemm_big<256, 256, 1024, 16, true>
            <<<dim3(16, 16), 512, DLDSB, stream>>>(xb, W1, fc1_b, h, 4096);
        // K2: prefill d_out with bias (xb scratch dead)
        bias_fill<<<4096, 256, 0, stream>>>(fc2_b, (float4*)d_out);
        // K3: GEMM2 -- 256x128, 128x64 wave tile, K-split 2, atomic +=
        gemm_sb2<256, 128, 2048, 4096, 8, 16>
            <<<dim3(8, 16, 2), 256, DLDS2, stream>>>(h, W2, (float*)d_out, 1024);
    } else {
        float* T1 = (float*)d_out;
        float* T2 = (float*)d_out + 524288;
        unsigned short* xb = (unsigned short*)((char*)d_out + (4u << 20));
        unsigned short* W = (unsigned short*)ws;
        unsigned short* h = (unsigned short*)(ws + (8u << 20));

        prep_stage1<<<6144, 256, 0, stream>>>(fc1_c1, fc1_c2, T1,
                                              fc2_c1, fc2_c2, T2, x, xb);
        build_W<8, 16, 8, 16, 16, 16><<<2048, 256, 0, stream>>>(fc1_c0, T1, W);
        gemm_pc<128, 128, 1024, true, false, false>
            <<<dim3(32, 32), 512, 0, stream>>>(xb, W, fc1_b, h, 4096);
        build_W<16, 16, 16, 8, 16, 8><<<1024, 256, 0, stream>>>(fc2_c0, T2, W);
        gemm_pc<128, 64, 4096, false, false, true>
            <<<dim3(16, 32), 512, 0, stream>>>(h, W, fc2_b, d_out, 1024);
    }
}

// Round 16
// 199.970 us; speedup vs baseline: 1.3727x; 1.3727x over previous
//
#include <hip/hip_runtime.h>
#include <stdint.h>

// ---------- bf16 helpers (storage = unsigned short) ----------
__device__ __forceinline__ float b2f(unsigned short u) {
    union { uint32_t i; float f; } v; v.i = ((uint32_t)u) << 16; return v.f;
}
__device__ __forceinline__ unsigned short f2b(float f) {
    union { float f; uint32_t i; } v; v.f = f;
    uint32_t r = v.i + 0x7fffu + ((v.i >> 16) & 1u);   // RNE
    return (unsigned short)(r >> 16);
}

typedef __bf16 bf16x8 __attribute__((ext_vector_type(8)));
typedef float  f32x16 __attribute__((ext_vector_type(16)));

// ---------------------------------------------------------------------------
// build_W_fused + prep_all: ONE launch for all pre-GEMM work (R11-verified).
// ---------------------------------------------------------------------------
template<int N1, int N2, int N3, int M1, int M2, int M3>
__device__ __forceinline__ void build_W_fused(int blk,
                                              const float* __restrict__ c0,
                                              const float* __restrict__ c1,
                                              const float* __restrict__ c2,
                                              unsigned short* __restrict__ W,
                                              float* __restrict__ S) {
    constexpr int K = N1 * N2 * N3;
    const int n2 = blk / M2;
    const int m2 = blk % M2;

    for (int e = threadIdx.x; e < 16 * N3 * M3; e += 256) {
        const int m3 = e % M3;
        const int n3 = (e / M3) % N3;
        const int r1 = e / (M3 * N3);
        const float* c1p = c1 + ((r1 * N2 + n2) * M2 + m2) * 16;
        float s = 0.f;
#pragma unroll
        for (int r2 = 0; r2 < 16; ++r2)
            s += c1p[r2] * c2[(r2 * N3 + n3) * M3 + m3];
        S[e] = s;
    }
    __syncthreads();

    for (int e = threadIdx.x; e < N1 * M1 * M3; e += 256) {
        const int m3 = e % M3;
        const int m1 = (e / M3) % M1;
        const int n1 = e / (M3 * M1);
        const float* c0p = c0 + (n1 * M1 + m1) * 16;
        float acc[N3] = {};
#pragma unroll
        for (int r1 = 0; r1 < 16; ++r1) {
            const float c0v = c0p[r1];
#pragma unroll
            for (int n3 = 0; n3 < N3; ++n3)
                acc[n3] += c0v * S[(r1 * N3 + n3) * M3 + m3];
        }
        unsigned short ob[N3];
#pragma unroll
        for (int n3 = 0; n3 < N3; ++n3) ob[n3] = f2b(acc[n3]);
        unsigned short* dst = W + (size_t)((m1 * M2 + m2) * M3 + m3) * K
                                + (n1 * N2 + n2) * N3;
#pragma unroll
        for (int c = 0; c < N3 / 8; ++c)
            ((int4*)dst)[c] = ((const int4*)ob)[c];
    }
}

__global__ __launch_bounds__(256)
void prep_all(const float* __restrict__ c10, const float* __restrict__ c11,
              const float* __restrict__ c12,
              const float* __restrict__ c20, const float* __restrict__ c21,
              const float* __restrict__ c22,
              const float* __restrict__ x, unsigned short* __restrict__ xb,
              unsigned short* __restrict__ W1, unsigned short* __restrict__ W2) {
    __shared__ float S[16 * 128];
    const int b = blockIdx.x;
    if (b < 256) {
        build_W_fused<8, 16, 8, 16, 16, 16>(b, c10, c11, c12, W1, S);
    } else if (b < 512) {
        build_W_fused<16, 16, 16, 8, 16, 8>(b - 256, c20, c21, c22, W2, S);
    } else {
        const int t = (b - 512) * 256 + threadIdx.x;
        const float4* p = (const float4*)(x + (size_t)t * 8);
        float4 f0 = p[0], f1 = p[1];
        int4 o;
        o.x = (uint32_t)f2b(f0.x) | ((uint32_t)f2b(f0.y) << 16);
        o.y = (uint32_t)f2b(f0.z) | ((uint32_t)f2b(f0.w) << 16);
        o.z = (uint32_t)f2b(f1.x) | ((uint32_t)f2b(f1.y) << 16);
        o.w = (uint32_t)f2b(f1.z) | ((uint32_t)f2b(f1.w) << 16);
        ((int4*)xb)[t] = o;
    }
}

// ---------------------------------------------------------------------------
// Fallback-path kernels (small workspace): verified R5-R7 chain.
// ---------------------------------------------------------------------------
template<int N3, int M3>
__device__ __forceinline__ void build_T_body(int e,
                                             const float* __restrict__ c1,
                                             const float* __restrict__ c2,
                                             float* __restrict__ T) {
    int m3 = e % M3;
    int t  = e / M3;
    int n3 = t % N3;
    int rm = t / N3;
    float s = 0.f;
#pragma unroll
    for (int r2 = 0; r2 < 16; ++r2)
        s += c1[rm * 16 + r2] * c2[(r2 * N3 + n3) * M3 + m3];
    T[e] = s;
}

__global__ __launch_bounds__(256)
void prep_stage1(const float* __restrict__ c11, const float* __restrict__ c12,
                 float* __restrict__ T1,
                 const float* __restrict__ c21, const float* __restrict__ c22,
                 float* __restrict__ T2,
                 const float* __restrict__ x, unsigned short* __restrict__ xb) {
    const int b = blockIdx.x;
    if (b < 2048) {
        build_T_body<8, 16>(b * 256 + threadIdx.x, c11, c12, T1);
    } else if (b < 4096) {
        build_T_body<16, 8>((b - 2048) * 256 + threadIdx.x, c21, c22, T2);
    } else {
        const int t = (b - 4096) * 256 + threadIdx.x;
        const float4* p = (const float4*)(x + (size_t)t * 8);
        float4 f0 = p[0], f1 = p[1];
        int4 o;
        o.x = (uint32_t)f2b(f0.x) | ((uint32_t)f2b(f0.y) << 16);
        o.y = (uint32_t)f2b(f0.z) | ((uint32_t)f2b(f0.w) << 16);
        o.z = (uint32_t)f2b(f1.x) | ((uint32_t)f2b(f1.y) << 16);
        o.w = (uint32_t)f2b(f1.z) | ((uint32_t)f2b(f1.w) << 16);
        ((int4*)xb)[t] = o;
    }
}

template<int N1, int N2, int N3, int M1, int M2, int M3>
__device__ __forceinline__ void build_W_body(int t,
                                             const float* __restrict__ c0,
                                             const float* __restrict__ T,
                                             unsigned short* __restrict__ W) {
    constexpr int K = N1 * N2 * N3;
    int m3 = t % M3;
    int m2 = (t / M3) % M2;
    int n2 = (t / (M3 * M2)) % N2;
    int m1 = (t / (M3 * M2 * N2)) % M1;
    int n1 =  t / (M3 * M2 * N2 * M1);

    float c0r[16];
    const float4* c0p = (const float4*)(c0 + (n1 * M1 + m1) * 16);
#pragma unroll
    for (int i = 0; i < 4; ++i) ((float4*)c0r)[i] = c0p[i];

    float acc[N3] = {};
#pragma unroll
    for (int r1 = 0; r1 < 16; ++r1) {
        const float* Tp = T + (size_t)(((r1 * 16 + n2) * 16 + m2) * N3) * M3 + m3;
#pragma unroll
        for (int n3 = 0; n3 < N3; ++n3)
            acc[n3] += c0r[r1] * Tp[n3 * M3];
    }

    unsigned short ob[N3];
#pragma unroll
    for (int n3 = 0; n3 < N3; ++n3) ob[n3] = f2b(acc[n3]);

    unsigned short* dst = W + (size_t)((m1 * M2 + m2) * M3 + m3) * K
                            + (n1 * N2 + n2) * N3;
#pragma unroll
    for (int c = 0; c < N3 / 8; ++c)
        ((int4*)dst)[c] = ((const int4*)ob)[c];
}

template<int N1, int N2, int N3, int M1, int M2, int M3>
__global__ __launch_bounds__(256)
void build_W(const float* __restrict__ c0, const float* __restrict__ T,
             unsigned short* __restrict__ W) {
    build_W_body<N1, N2, N3, M1, M2, M3>(blockIdx.x * 256 + threadIdx.x, c0, T, W);
}

// ---------------------------------------------------------------------------
// gemm_big: 256x256 tile, 8 waves, 128x64 WAVE TILE (R13-verified, ~50.6us,
// 687 TF -- the measured 2-phase-family ceiling, m230: 682).
// 2-phase dbuf loop: STAGE(buf^1, t+1) -> COMPUTE(buf) -> __syncthreads.
// DO NOT hold full-tile frags in regs (R14: spills, WRITE 92.8MB, 119us).
// DO NOT starve occupancy (R15: 1 block/CU x 4 waves = 128us).
// Staging pre-swizzled gload_lds, key(r)=(r&7)^((r>>3)&7), 0 conflicts.
// C/D map (m74/m101): col=lane&31, row=(reg&3)+8*(reg>>2)+4*(lane>>5).
// ---------------------------------------------------------------------------
template<int BM, int BN, int KTOT, int GX, bool DO_GELU>
__global__ __launch_bounds__(512, 2)
void gemm_big(const unsigned short* __restrict__ A,
              const unsigned short* __restrict__ Bt,
              const float* __restrict__ bias,
              unsigned short* __restrict__ C,
              int Ncols)
{
    constexpr int BK   = 64;
    constexpr int NT   = KTOT / BK;
    constexpr int ASZ  = BM * BK;          // 16384 elems (32KB)
    constexpr int BUFE = (BM + BN) * BK;   // 32768 elems (64KB)
    constexpr int ACH  = BM / 64;          // 4
    constexpr int BCH  = BN / 64;          // 4
    constexpr int FI   = 4, FJ = 2;        // 128x64 wave tile

    extern __shared__ unsigned short sh[];   // [2][BUFE]

    const int tid   = threadIdx.x;
    const int lane  = tid & 63;
    const int wave  = tid >> 6;            // 0..7
    const int m32   = lane & 31;
    const int khalf = lane >> 5;
    const int waveM = (wave >> 2) * 128;   // 2 M-waves
    const int waveN = (wave & 3) * 64;     // 4 N-waves
    const int srow  = tid >> 3;            // 0..63
    const int sslot = tid & 7;

    // XCD-chunked bijective block swizzle (total = 256, %8==0)
    int lin = (int)blockIdx.y * GX + (int)blockIdx.x;
    const int total = GX * (int)gridDim.y;
    lin = (lin & 7) * (total >> 3) + (lin >> 3);
    const int colBase = (lin % GX) * BN;
    const int rowBase = (lin / GX) * BM;

#define BG_STAGE(B_, K0_)                                                     \
    {                                                                         \
        _Pragma("unroll")                                                     \
        for (int c = 0; c < ACH; ++c) {                                       \
            const int r  = c * 64 + srow;                                     \
            const int jg = sslot ^ (r & 7) ^ ((r >> 3) & 7);                  \
            const unsigned short* src = A +                                   \
                (size_t)(rowBase + r) * KTOT + (K0_) + jg * 8;                \
            unsigned short* dst = sh + (B_) * BUFE + c * 4096 + wave * 512;   \
            __builtin_amdgcn_global_load_lds(                                 \
                (const __attribute__((address_space(1))) void*)src,           \
                (__attribute__((address_space(3))) void*)dst, 16, 0, 0);      \
        }                                                                     \
        _Pragma("unroll")                                                     \
        for (int c = 0; c < BCH; ++c) {                                       \
            const int r  = c * 64 + srow;                                     \
            const int jg = sslot ^ (r & 7) ^ ((r >> 3) & 7);                  \
            const unsigned short* src = Bt +                                  \
                (size_t)(colBase + r) * KTOT + (K0_) + jg * 8;                \
            unsigned short* dst = sh + (B_) * BUFE + ASZ + c * 4096           \
                                  + wave * 512;                               \
            __builtin_amdgcn_global_load_lds(                                 \
                (const __attribute__((address_space(1))) void*)src,           \
                (__attribute__((address_space(3))) void*)dst, 16, 0, 0);      \
        }                                                                     \
    }

    f32x16 acc[FI][FJ] = {};

    BG_STAGE(0, 0)
    __syncthreads();

    int buf = 0;
    for (int t = 0; t < NT; ++t) {
        if (t + 1 < NT) BG_STAGE(buf ^ 1, (t + 1) * BK)

        const unsigned short* Ab = sh + buf * BUFE;
        const unsigned short* Bb = Ab + ASZ;
#pragma unroll
        for (int ks = 0; ks < 4; ++ks) {
            bf16x8 a_f[FI], b_f[FJ];
            const int g = ks * 2 + khalf;
#pragma unroll
            for (int i = 0; i < FI; ++i) {
                const int r = waveM + i * 32 + m32;
                const int key = (r & 7) ^ ((r >> 3) & 7);
                a_f[i] = *(const bf16x8*)&Ab[r * BK + ((g ^ key) << 3)];
            }
#pragma unroll
            for (int j = 0; j < FJ; ++j) {
                const int r = waveN + j * 32 + m32;
                const int key = (r & 7) ^ ((r >> 3) & 7);
                b_f[j] = *(const bf16x8*)&Bb[r * BK + ((g ^ key) << 3)];
            }
#pragma unroll
            for (int i = 0; i < FI; ++i)
#pragma unroll
                for (int j = 0; j < FJ; ++j)
                    acc[i][j] = __builtin_amdgcn_mfma_f32_32x32x16_bf16(
                        a_f[i], b_f[j], acc[i][j], 0, 0, 0);
        }
        __syncthreads();
        buf ^= 1;
    }
#undef BG_STAGE

    // epilogue: col=lane&31, row=(reg&3)+8*(reg>>2)+4*(lane>>5)
#pragma unroll
    for (int i = 0; i < FI; ++i) {
#pragma unroll
        for (int j = 0; j < FJ; ++j) {
            const int col = colBase + waveN + j * 32 + m32;
            const float bv = bias[col];
#pragma unroll
            for (int reg = 0; reg < 16; ++reg) {
                const int row = rowBase + waveM + i * 32 +
                                (reg & 3) + 8 * (reg >> 2) + 4 * khalf;
                float z = acc[i][j][reg] + bv;
                if (DO_GELU)
                    z = 0.5f * z * (1.f + erff(z * 0.70710678118654752f));
                C[(size_t)row * Ncols + col] = f2b(z);
            }
        }
    }
}

// ---------------------------------------------------------------------------
// gemm_sb: SINGLE-buffered BK=64 2-barrier loop (R10-R13-verified, GEMM2:
// 58.7us / 586 TF at 2 blocks/CU x 4 waves).  40KB LDS request caps
// occupancy at the gload_lds-safe 4 blocks/CU.
// ---------------------------------------------------------------------------
template<int BM, int BN, int KCH, int KSTR, int GX, int GY,
         bool DO_GELU, bool ATOMIC>
__global__ __launch_bounds__(256, 4)
void gemm_sb(const unsigned short* __restrict__ A,
             const unsigned short* __restrict__ Bt,
             const float* __restrict__ bias,
             void* __restrict__ Cv,
             int Ncols)
{
    constexpr int BK  = 64;
    constexpr int NT  = KCH / BK;
    constexpr int ASZ = BM * BK;
    constexpr int ACH = BM / 32;
    constexpr int BCH = BN / 32;
    constexpr int FI  = BM / 64, FJ = BN / 64;

    extern __shared__ unsigned short sh[];

    const int tid   = threadIdx.x;
    const int lane  = tid & 63;
    const int wave  = tid >> 6;
    const int m32   = lane & 31;
    const int khalf = lane >> 5;
    const int waveM = (wave >> 1) * (BM / 2);
    const int waveN = (wave & 1) * (BN / 2);
    const int srow  = tid >> 3;
    const int sslot = tid & 7;

    int lin = ((int)blockIdx.z * GY + (int)blockIdx.y) * GX + (int)blockIdx.x;
    const int total = GX * GY * (int)gridDim.z;
    lin = (lin & 7) * (total >> 3) + (lin >> 3);
    const int colBase = (lin % GX) * BN;
    const int rowBase = ((lin / GX) % GY) * BM;
    const int kOff    = (lin / (GX * GY)) * KCH;

#define SB_STAGE(K0_)                                                         \
    {                                                                         \
        _Pragma("unroll")                                                     \
        for (int c = 0; c < ACH; ++c) {                                       \
            const int r  = c * 32 + srow;                                     \
            const int jg = sslot ^ (r & 7) ^ ((r >> 3) & 7);                  \
            const unsigned short* src = A +                                   \
                (size_t)(rowBase + r) * KSTR + (K0_) + jg * 8;                \
            unsigned short* dst = sh + c * 2048 + wave * 512;                 \
            __builtin_amdgcn_global_load_lds(                                 \
                (const __attribute__((address_space(1))) void*)src,           \
                (__attribute__((address_space(3))) void*)dst, 16, 0, 0);      \
        }                                                                     \
        _Pragma("unroll")                                                     \
        for (int c = 0; c < BCH; ++c) {                                       \
            const int r  = c * 32 + srow;                                     \
            const int jg = sslot ^ (r & 7) ^ ((r >> 3) & 7);                  \
            const unsigned short* src = Bt +                                  \
                (size_t)(colBase + r) * KSTR + (K0_) + jg * 8;                \
            unsigned short* dst = sh + ASZ + c * 2048 + wave * 512;           \
            __builtin_amdgcn_global_load_lds(                                 \
                (const __attribute__((address_space(1))) void*)src,           \
                (__attribute__((address_space(3))) void*)dst, 16, 0, 0);      \
        }                                                                     \
    }

    f32x16 acc[FI][FJ] = {};

    for (int t = 0; t < NT; ++t) {
        SB_STAGE(kOff + t * BK)
        __syncthreads();

        const unsigned short* Ab = sh;
        const unsigned short* Bb = sh + ASZ;
#pragma unroll
        for (int ks = 0; ks < 4; ++ks) {
            bf16x8 a_f[FI], b_f[FJ];
            const int g = ks * 2 + khalf;
#pragma unroll
            for (int i = 0; i < FI; ++i) {
                const int r = waveM + i * 32 + m32;
                const int key = (r & 7) ^ ((r >> 3) & 7);
                a_f[i] = *(const bf16x8*)&Ab[r * BK + ((g ^ key) << 3)];
            }
#pragma unroll
            for (int j = 0; j < FJ; ++j) {
                const int r = waveN + j * 32 + m32;
                const int key = (r & 7) ^ ((r >> 3) & 7);
                b_f[j] = *(const bf16x8*)&Bb[r * BK + ((g ^ key) << 3)];
            }
#pragma unroll
            for (int i = 0; i < FI; ++i)
#pragma unroll
                for (int j = 0; j < FJ; ++j)
                    acc[i][j] = __builtin_amdgcn_mfma_f32_32x32x16_bf16(
                        a_f[i], b_f[j], acc[i][j], 0, 0, 0);
        }
        if (t + 1 < NT) __syncthreads();
    }
#undef SB_STAGE

#pragma unroll
    for (int i = 0; i < FI; ++i) {
#pragma unroll
        for (int j = 0; j < FJ; ++j) {
            const int col = colBase + waveN + j * 32 + m32;
            const float bv = ATOMIC ? 0.f : bias[col];
#pragma unroll
            for (int reg = 0; reg < 16; ++reg) {
                const int row = rowBase + waveM + i * 32 +
                                (reg & 3) + 8 * (reg >> 2) + 4 * khalf;
                const size_t off = (size_t)row * Ncols + col;
                if (ATOMIC) {
                    unsafeAtomicAdd((float*)Cv + off, acc[i][j][reg]);
                } else {
                    float z = acc[i][j][reg] + bv;
                    if (DO_GELU) {
                        z = 0.5f * z * (1.f + erff(z * 0.70710678118654752f));
                        ((unsigned short*)Cv)[off] = f2b(z);
                    } else {
                        ((float*)Cv)[off] = z;
                    }
                }
            }
        }
    }
}

// ---------------------------------------------------------------------------
// gemm_pc: R0's producer-consumer GEMM (fallback path only).
// ---------------------------------------------------------------------------
#define PC_COMPUTE(BUF)                                                       \
    {                                                                         \
        _Pragma("unroll")                                                     \
        for (int ks = 0; ks < 4; ++ks) {                                      \
            bf16x8 a_f[FI], b_f[FJ];                                          \
            _Pragma("unroll")                                                 \
            for (int i = 0; i < FI; ++i) {                                    \
                const int key = (m32 & 7) ^                                   \
                    (((waveM >> 3) + 4 * i + (m32 >> 3)) & 7);                \
                const int slot = ((ks * 2 + khalf) ^ key) * 8;                \
                a_f[i] = *(const bf16x8*)&As[(BUF) * ASZ +                    \
                          (waveM + i * 32 + m32) * BK + slot];                \
            }                                                                 \
            _Pragma("unroll")                                                 \
            for (int j = 0; j < FJ; ++j) {                                    \
                const int key = (m32 & 7) ^                                   \
                    (((waveN >> 3) + 4 * j + (m32 >> 3)) & 7);                \
                const int slot = ((ks * 2 + khalf) ^ key) * 8;                \
                b_f[j] = *(const bf16x8*)&Bs[(BUF) * BSZ +                    \
                          (waveN + j * 32 + m32) * BK + slot];                \
            }                                                                 \
            _Pragma("unroll")                                                 \
            for (int i = 0; i < FI; ++i)                                      \
                _Pragma("unroll")                                             \
                for (int j = 0; j < FJ; ++j)                                  \
                    acc[i][j] = __builtin_amdgcn_mfma_f32_32x32x16_bf16(      \
                        a_f[i], b_f[j], acc[i][j], 0, 0, 0);                  \
        }                                                                     \
    }

template<int BM, int BN, int KTOT, bool DO_GELU, bool A_F32, bool C_F32>
__global__ __launch_bounds__(512, 4)
void gemm_pc(const void* __restrict__ Av,
             const unsigned short* __restrict__ Bt,
             const float* __restrict__ bias,
             void* __restrict__ Cv,
             int Ncols) {
    constexpr int BK  = 64;
    constexpr int CA  = BM / 8;
    constexpr int CB  = BN / 8;
    constexpr int PA  = CA / 4;
    constexpr int PB  = CB / 4;
    constexpr int FI  = BM / 64;
    constexpr int FJ  = BN / 64;
    constexpr int ASZ = BM * BK;
    constexpr int BSZ = BN * BK;
    __shared__ unsigned short As[2 * ASZ];
    __shared__ unsigned short Bs[2 * BSZ];

    const int tid  = threadIdx.x;
    const int lane = tid & 63;
    const int wave = tid >> 6;
    const int rowBase = blockIdx.y * BM;
    const int colBase = blockIdx.x * BN;

    const int lr    = lane >> 3;
    const int jj    = lane & 7;
    const int m32   = lane & 31;
    const int khalf = lane >> 5;

    if (wave >= 4) {
        const int pw = wave - 4;
#pragma unroll
        for (int it = 0; it < PA; ++it) {
            const int c  = pw * PA + it;
            const int jg = jj ^ lr ^ (c & 7);
            const size_t aoff = (size_t)(rowBase + c * 8 + lr) * KTOT + jg * 8;
            int4 v;
            if (A_F32) {
                const float* ga = (const float*)Av + aoff;
                float4 f0 = *(const float4*)ga;
                float4 f1 = *(const float4*)(ga + 4);
                v.x = (uint32_t)f2b(f0.x) | ((uint32_t)f2b(f0.y) << 16);
                v.y = (uint32_t)f2b(f0.z) | ((uint32_t)f2b(f0.w) << 16);
                v.z = (uint32_t)f2b(f1.x) | ((uint32_t)f2b(f1.y) << 16);
                v.w = (uint32_t)f2b(f1.z) | ((uint32_t)f2b(f1.w) << 16);
            } else {
                v = *(const int4*)((const unsigned short*)Av + aoff);
            }
            *(int4*)&As[c * 512 + lane * 8] = v;
        }
#pragma unroll
        for (int it = 0; it < PB; ++it) {
            const int c  = pw * PB + it;
            const int jg = jj ^ lr ^ (c & 7);
            *(int4*)&Bs[c * 512 + lane * 8] =
                *(const int4*)(Bt + (size_t)(colBase + c * 8 + lr) * KTOT + jg * 8);
        }
        __syncthreads();

        int buf = 1;
        for (int k0 = BK; k0 < KTOT; k0 += BK) {
            int4 aR[PA], bR[PB];
#pragma unroll
            for (int it = 0; it < PA; ++it) {
                const int c  = pw * PA + it;
                const int jg = jj ^ lr ^ (c & 7);
                const size_t aoff = (size_t)(rowBase + c * 8 + lr) * KTOT + k0 + jg * 8;
                if (A_F32) {
                    const float* ga = (const float*)Av + aoff;
                    float4 f0 = *(const float4*)ga;
                    float4 f1 = *(const float4*)(ga + 4);
                    int4 v;
                    v.x = (uint32_t)f2b(f0.x) | ((uint32_t)f2b(f0.y) << 16);
                    v.y = (uint32_t)f2b(f0.z) | ((uint32_t)f2b(f0.w) << 16);
                    v.z = (uint32_t)f2b(f1.x) | ((uint32_t)f2b(f1.y) << 16);
                    v.w = (uint32_t)f2b(f1.z) | ((uint32_t)f2b(f1.w) << 16);
                    aR[it] = v;
                } else {
                    aR[it] = *(const int4*)((const unsigned short*)Av + aoff);
                }
            }
#pragma unroll
            for (int it = 0; it < PB; ++it) {
                const int c  = pw * PB + it;
                const int jg = jj ^ lr ^ (c & 7);
                bR[it] = *(const int4*)(Bt + (size_t)(colBase + c * 8 + lr) * KTOT + k0 + jg * 8);
            }
#pragma unroll
            for (int it = 0; it < PA; ++it) {
                const int c = pw * PA + it;
                *(int4*)&As[buf * ASZ + c * 512 + lane * 8] = aR[it];
            }
#pragma unroll
            for (int it = 0; it < PB; ++it) {
                const int c = pw * PB + it;
                *(int4*)&Bs[buf * BSZ + c * 512 + lane * 8] = bR[it];
            }
            __syncthreads();
            buf ^= 1;
        }
    } else {
        const int waveM = (wave >> 1) * (BM / 2);
        const int waveN = (wave & 1) * (BN / 2);
        f32x16 acc[FI][FJ] = {};

        __syncthreads();

        int cur = 0;
        for (int k0 = BK; k0 < KTOT; k0 += BK) {
            PC_COMPUTE(cur)
            __syncthreads();
            cur ^= 1;
        }
        PC_COMPUTE(cur)

#pragma unroll
        for (int i = 0; i < FI; ++i) {
#pragma unroll
            for (int j = 0; j < FJ; ++j) {
                const int col = colBase + waveN + j * 32 + m32;
                const float bv = bias[col];
#pragma unroll
                for (int reg = 0; reg < 16; ++reg) {
                    const int row = rowBase + waveM + i * 32 +
                                    (reg & 3) + 8 * (reg >> 2) + 4 * khalf;
                    float z = acc[i][j][reg] + bv;
                    if (DO_GELU)
                        z = 0.5f * z * (1.f + erff(z * 0.70710678118654752f));
                    const size_t off = (size_t)row * Ncols + col;
                    if (C_F32) ((float*)Cv)[off] = z;
                    else       ((unsigned short*)Cv)[off] = f2b(z);
                }
            }
        }
    }
}

// ---------------------------------------------------------------------------
extern "C" void kernel_launch(void* const* d_in, const int* in_sizes, int n_in,
                              void* d_out, int out_size, void* d_ws, size_t ws_size,
                              hipStream_t stream) {
    const float* x      = (const float*)d_in[0];   // [4096,1024] fp32
    const float* fc1_c0 = (const float*)d_in[1];
    const float* fc1_c1 = (const float*)d_in[2];
    const float* fc1_c2 = (const float*)d_in[3];
    const float* fc1_b  = (const float*)d_in[4];
    const float* fc2_c0 = (const float*)d_in[5];
    const float* fc2_c1 = (const float*)d_in[6];
    const float* fc2_c2 = (const float*)d_in[7];
    const float* fc2_b  = (const float*)d_in[8];

    char* ws = (char*)d_ws;
    const bool big = ws_size >= (48ull << 20);

    constexpr int DLDSB = 2 * (256 + 256) * 64 * 2;  // 128 KB dbuf (gemm_big)
    constexpr int DLDS  = 40 << 10;                  // gemm_sb: 4 blocks/CU

    static bool attr_done = false;
    if (!attr_done) {
        attr_done = true;
        (void)hipFuncSetAttribute(
            reinterpret_cast<const void*>(&gemm_big<256, 256, 1024, 16, true>),
            hipFuncAttributeMaxDynamicSharedMemorySize, DLDSB);
    }

    if (big) {
        // d_out scratch: xb bf16 [0,8M) -- dead before GEMM2 writes d_out.
        // ws: W1 [0,8M), W2 [8,16M), h bf16 [16,48M)
        unsigned short* xb = (unsigned short*)d_out;
        unsigned short* W1 = (unsigned short*)ws;
        unsigned short* W2 = (unsigned short*)(ws + (8u << 20));
        unsigned short* h  = (unsigned short*)(ws + (16u << 20));

        // K0: all pre-GEMM work in one launch (R11-verified)
        prep_all<<<2560, 256, 0, stream>>>(fc1_c0, fc1_c1, fc1_c2,
                                           fc2_c0, fc2_c1, fc2_c2,
                                           x, xb, W1, W2);
        // K1: GEMM1 -- 256x256 tile, 128x64 wave tile, grid 16x16 = 256
        gemm_big<256, 256, 1024, 16, true>
            <<<dim3(16, 16), 512, DLDSB, stream>>>(xb, W1, fc1_b, h, 4096);
        // K2: GEMM2 -- R11-R13-proven gemm_sb direct-write
        gemm_sb<128, 64, 4096, 4096, 16, 32, false, false>
            <<<dim3(16, 32, 1), 256, DLDS, stream>>>(h, W2, fc2_b, d_out, 1024);
    } else {
        float* T1 = (float*)d_out;
        float* T2 = (float*)d_out + 524288;
        unsigned short* xb = (unsigned short*)((char*)d_out + (4u << 20));
        unsigned short* W = (unsigned short*)ws;
        unsigned short* h = (unsigned short*)(ws + (8u << 20));

        prep_stage1<<<6144, 256, 0, stream>>>(fc1_c1, fc1_c2, T1,
                                              fc2_c1, fc2_c2, T2, x, xb);
        build_W<8, 16, 8, 16, 16, 16><<<2048, 256, 0, stream>>>(fc1_c0, T1, W);
        gemm_pc<128, 128, 1024, true, false, false>
            <<<dim3(32, 32), 512, 0, stream>>>(xb, W, fc1_b, h, 4096);
        build_W<16, 16, 16, 8, 16, 8><<<1024, 256, 0, stream>>>(fc2_c0, T2, W);
        gemm_pc<128, 64, 4096, false, false, true>
            <<<dim3(16, 32), 512, 0, stream>>>(h, W, fc2_b, d_out, 1024);
    }
}